// Round 5
// baseline (250.803 us; speedup 1.0000x reference)
//
#include <hip/hip_runtime.h>

#define NK 512
#define ND 64
#define NHW 4096
#define NPIX 131072            // 32*64*64
#define OUT_ELEMS 8388608      // 32*64*64*64

typedef float f4  __attribute__((ext_vector_type(4)));
typedef float f16 __attribute__((ext_vector_type(16)));

// ---------------------------------------------------------------------------
// Prep: sc[k] = numpy-pairwise-8 fp32 sum of fl(c_d^2) into d_ws; zero the
// two loss slots (harness re-poisons d_out/d_ws to 0xAA every replay).
// ---------------------------------------------------------------------------
__global__ __launch_bounds__(256) void vq_prep(const float* __restrict__ cb,
                                               float* __restrict__ sc,
                                               float* __restrict__ losses) {
#pragma clang fp contract(off)
  {
    int k = blockIdx.x * 256 + threadIdx.x;   // grid 2*256 = 512
    const float* c = cb + (size_t)k * ND;
    float q[ND];
#pragma unroll
    for (int d = 0; d < ND; ++d) q[d] = c[d] * c[d];
    float r[8];
#pragma unroll
    for (int j = 0; j < 8; ++j) r[j] = q[j];
#pragma unroll
    for (int i = 8; i < ND; i += 8)
#pragma unroll
      for (int j = 0; j < 8; ++j) r[j] += q[i + j];
    sc[k] = ((r[0] + r[1]) + (r[2] + r[3])) + ((r[4] + r[5]) + (r[6] + r[7]));
    if (k < 2) losses[k] = 0.f;
  }
}

// ---------------------------------------------------------------------------
// Main: lane = pixel; codebook streamed through SGPRs via explicit
// s_load_dwordx16; x in 16 named f4 VGPR vectors.
// R4 post-mortem: VGPR_Count=44 (< the 64 x needs) at a 128-reg budget, and
// VALU time 2.3x the FMA floor -> the compiler rematerialized/AGPR-shuffled
// x, and the "+s"-tied waitcnt asms redefined the 512-bit tuples 1024x per
// wave (live-range splits). R5 fixes lifetimes, keeps the schedule:
//   (1) pin x + Sx with "+v" identity asm (asm-defined values can't be
//       rematerialized -> x stays in arch VGPRs);
//   (2) bare s_waitcnt lgkmcnt(0) + sched_barrier(0) (rule-#18 pattern)
//       instead of "+s" ties -> each SGPR tuple has ONE def per iteration.
// K is split: waves 0,1 -> codes 0..255, waves 2,3 -> 256..511 for the same
// 128 pixels; grid 1024 blocks = 4 blocks/CU = 4 waves/SIMD; 4 half-duty
// dependent FMA chains saturate VALU issue.
// Numerics bit-identical to all passing versions: per-(n,k) sequential fp32
// FMA chain d=0..63 (dq ascending, component order within quad); d2 =
// fl(fl(Sx - fl(2a)) + Sc) (2a exact in fp32); Sx/sc numpy pairwise-8 of
// rounded squares; candidates ascend in code with strict '<'; cross-half
// tie keeps low half => lowest index wins = np.argmin.
// ---------------------------------------------------------------------------
__global__ __launch_bounds__(256, 4) void vq_main(const float* __restrict__ x,
                                                  const float* __restrict__ cb,
                                                  const float* __restrict__ sc,
                                                  float* __restrict__ out,
                                                  float* __restrict__ idx_out,
                                                  float* __restrict__ losses) {
#pragma clang fp contract(off)
  {
    __shared__ float him[128];
    __shared__ int   hii[128];
    __shared__ float red[2];

    const int tid = threadIdx.x;
    const int wv = tid >> 6;                 // 0..3
    const int lane = tid & 63;
    const int pxl = ((wv & 1) << 6) | lane;  // local pixel 0..127
    const int px = blockIdx.x * 128 + pxl;
    const int b = px >> 12;
    const int hw = px & 4095;
    const float* xp = x + (size_t)b * (ND * NHW) + hw;

    // ---- x into 16 named f4 registers (coalesced dword loads).
    f4 xv0, xv1, xv2, xv3, xv4, xv5, xv6, xv7;
    f4 xv8, xv9, xv10, xv11, xv12, xv13, xv14, xv15;
#define LX(V, D)                           \
    V[0] = xp[(size_t)(D + 0) * NHW];      \
    V[1] = xp[(size_t)(D + 1) * NHW];      \
    V[2] = xp[(size_t)(D + 2) * NHW];      \
    V[3] = xp[(size_t)(D + 3) * NHW];
    LX(xv0, 0)  LX(xv1, 4)  LX(xv2, 8)   LX(xv3, 12)
    LX(xv4, 16) LX(xv5, 20) LX(xv6, 24)  LX(xv7, 28)
    LX(xv8, 32) LX(xv9, 36) LX(xv10, 40) LX(xv11, 44)
    LX(xv12, 48) LX(xv13, 52) LX(xv14, 56) LX(xv15, 60)
#undef LX

    // ---- Sx: rounded squares, pairwise-8 (bitwise = prior rounds).
    float rr0 = xv0[0] * xv0[0], rr1 = xv0[1] * xv0[1];
    float rr2 = xv0[2] * xv0[2], rr3 = xv0[3] * xv0[3];
    float rr4 = xv1[0] * xv1[0], rr5 = xv1[1] * xv1[1];
    float rr6 = xv1[2] * xv1[2], rr7 = xv1[3] * xv1[3];
#define SXA(E, O)                                          \
    rr0 += E[0] * E[0]; rr1 += E[1] * E[1];                \
    rr2 += E[2] * E[2]; rr3 += E[3] * E[3];                \
    rr4 += O[0] * O[0]; rr5 += O[1] * O[1];                \
    rr6 += O[2] * O[2]; rr7 += O[3] * O[3];
    SXA(xv2, xv3) SXA(xv4, xv5) SXA(xv6, xv7)
    SXA(xv8, xv9) SXA(xv10, xv11) SXA(xv12, xv13) SXA(xv14, xv15)
#undef SXA
    float Sx = ((rr0 + rr1) + (rr2 + rr3)) + ((rr4 + rr5) + (rr6 + rr7));

    // ---- PIN x and Sx: asm-defined values cannot be rematerialized, so
    // the 64 x floats stay resident in arch VGPRs across the K-loop
    // (R4's VGPR_Count=44 proved they were being spilled/remat'd).
    asm volatile("" : "+v"(xv0), "+v"(xv1), "+v"(xv2), "+v"(xv3));
    asm volatile("" : "+v"(xv4), "+v"(xv5), "+v"(xv6), "+v"(xv7));
    asm volatile("" : "+v"(xv8), "+v"(xv9), "+v"(xv10), "+v"(xv11));
    asm volatile("" : "+v"(xv12), "+v"(xv13), "+v"(xv14), "+v"(xv15));
    asm volatile("" : "+v"(Sx));

    // ---- K loop: this wave's 256 codes via SGPR half-code streaming.
    const int k0 = (wv >> 1) << 8;                  // 0 or 256 (wave-uniform)
    const float* scu = sc + k0;

    // Launder the wave-uniform codebook base into the scalar domain.
    const unsigned long long baddr =
        (unsigned long long)(const void*)(cb + (size_t)k0 * ND);
    const unsigned int blo = __builtin_amdgcn_readfirstlane((unsigned int)baddr);
    const unsigned int bhi = __builtin_amdgcn_readfirstlane((unsigned int)(baddr >> 32));
    const unsigned long long base = ((unsigned long long)bhi << 32) | blo;

    f16 A0, A1, B0, B1;
    // Prologue: A <- dims 0..31 of code 0.
    asm volatile("s_load_dwordx16 %0, %2, 0x0\n\t"
                 "s_load_dwordx16 %1, %2, 0x40"
                 : "=s"(A0), "=s"(A1) : "s"(base));
    asm volatile("s_waitcnt lgkmcnt(0)");
    __builtin_amdgcn_sched_barrier(0);

    float m = 3.0e38f;
    int best = 0;

#define FMA16(T, Q0, Q1, Q2, Q3)                                \
    a = __builtin_fmaf(T[0],  Q0[0], a);                        \
    a = __builtin_fmaf(T[1],  Q0[1], a);                        \
    a = __builtin_fmaf(T[2],  Q0[2], a);                        \
    a = __builtin_fmaf(T[3],  Q0[3], a);                        \
    a = __builtin_fmaf(T[4],  Q1[0], a);                        \
    a = __builtin_fmaf(T[5],  Q1[1], a);                        \
    a = __builtin_fmaf(T[6],  Q1[2], a);                        \
    a = __builtin_fmaf(T[7],  Q1[3], a);                        \
    a = __builtin_fmaf(T[8],  Q2[0], a);                        \
    a = __builtin_fmaf(T[9],  Q2[1], a);                        \
    a = __builtin_fmaf(T[10], Q2[2], a);                        \
    a = __builtin_fmaf(T[11], Q2[3], a);                        \
    a = __builtin_fmaf(T[12], Q3[0], a);                        \
    a = __builtin_fmaf(T[13], Q3[1], a);                        \
    a = __builtin_fmaf(T[14], Q3[2], a);                        \
    a = __builtin_fmaf(T[15], Q3[3], a);

#define VQ_CODE(U, SCQC)                                                      \
    {                                                                         \
      const int kk = q4 + U;                                                  \
      const unsigned long long ca = base + ((unsigned long long)kk << 8);     \
      /* issue B <- dims 32..63 of code kk */                                 \
      asm volatile("s_load_dwordx16 %0, %2, 0x80\n\t"                         \
                   "s_load_dwordx16 %1, %2, 0xc0"                             \
                   : "=s"(B0), "=s"(B1) : "s"(ca));                           \
      float a = 0.f;                                                          \
      FMA16(A0, xv0, xv1, xv2, xv3)        /* dims 0..15  */                  \
      FMA16(A1, xv4, xv5, xv6, xv7)        /* dims 16..31 */                  \
      asm volatile("s_waitcnt lgkmcnt(0)");                                   \
      __builtin_amdgcn_sched_barrier(0);                                      \
      /* issue A <- dims 0..31 of next code (clamped, uniform) */             \
      const unsigned long long cn =                                           \
          base + ((unsigned long long)((kk < 255) ? kk + 1 : 255) << 8);      \
      asm volatile("s_load_dwordx16 %0, %2, 0x0\n\t"                          \
                   "s_load_dwordx16 %1, %2, 0x40"                             \
                   : "=s"(A0), "=s"(A1) : "s"(cn));                           \
      FMA16(B0, xv8, xv9, xv10, xv11)      /* dims 32..47 */                  \
      FMA16(B1, xv12, xv13, xv14, xv15)    /* dims 48..63 */                  \
      const float d2 = (Sx - 2.0f * a) + SCQC;                                \
      if (d2 < m) { m = d2; best = k0 + kk; }                                 \
      asm volatile("s_waitcnt lgkmcnt(0)");                                   \
      __builtin_amdgcn_sched_barrier(0);                                      \
    }

    for (int q = 0; q < 64; ++q) {
      const int q4 = q * 4;
      const f4 scq = *(const f4*)(scu + q4);   // uniform values, tiny load
      VQ_CODE(0, scq[0])
      VQ_CODE(1, scq[1])
      VQ_CODE(2, scq[2])
      VQ_CODE(3, scq[3])
    }
#undef VQ_CODE
#undef FMA16

    // ---- Cross-half argmin: high half (waves 2,3) publishes; low half
    // combines with strict '<' (tie keeps low half's lower index).
    if (wv >= 2) { him[pxl] = m; hii[pxl] = best; }
    __syncthreads();

    float lossp = 0.f;
    if (wv < 2) {
      const float mh = him[pxl];
      const int ih = hii[pxl];
      if (mh < m) { m = mh; best = ih; }
      idx_out[px] = (float)best;
      const float* qrow = cb + (size_t)best * ND;
      float* op = out + (size_t)b * (ND * NHW) + hw;
#define EPI(Q, D)                                                             \
      {                                                                       \
        const f4 qv = *(const f4*)(qrow + D);                                 \
        float e;                                                              \
        e = Q[0] - qv[0]; lossp = __builtin_fmaf(e, e, lossp); op[(size_t)(D + 0) * NHW] = qv[0]; \
        e = Q[1] - qv[1]; lossp = __builtin_fmaf(e, e, lossp); op[(size_t)(D + 1) * NHW] = qv[1]; \
        e = Q[2] - qv[2]; lossp = __builtin_fmaf(e, e, lossp); op[(size_t)(D + 2) * NHW] = qv[2]; \
        e = Q[3] - qv[3]; lossp = __builtin_fmaf(e, e, lossp); op[(size_t)(D + 3) * NHW] = qv[3]; \
      }
      EPI(xv0, 0)  EPI(xv1, 4)  EPI(xv2, 8)   EPI(xv3, 12)
      EPI(xv4, 16) EPI(xv5, 20) EPI(xv6, 24)  EPI(xv7, 28)
      EPI(xv8, 32) EPI(xv9, 36) EPI(xv10, 40) EPI(xv11, 44)
      EPI(xv12, 48) EPI(xv13, 52) EPI(xv14, 56) EPI(xv15, 60)
#undef EPI
    }
#pragma unroll
    for (int off = 32; off; off >>= 1) lossp += __shfl_down(lossp, off);
    if (lane == 0 && wv < 2) red[wv] = lossp;
    __syncthreads();
    if (tid == 0) {
      float t = (red[0] + red[1]) * (1.f / 8388608.f);
      atomicAdd(losses + 0, t);   // dictionary_loss
      atomicAdd(losses + 1, t);   // commitment_loss (identical forward value)
    }
  }
}

extern "C" void kernel_launch(void* const* d_in, const int* in_sizes, int n_in,
                              void* d_out, int out_size, void* d_ws, size_t ws_size,
                              hipStream_t stream) {
  const float* x  = (const float*)d_in[0];   // [32,64,64,64] fp32
  const float* cb = (const float*)d_in[1];   // [512,64] fp32
  float* out     = (float*)d_out;            // quantized [B,D,H,W]
  float* idx_out = out + OUT_ELEMS;          // indices (as fp32) [B,H,W]
  float* losses  = idx_out + NPIX;           // 2 scalars
  float* sc      = (float*)d_ws;             // 512 floats scratch

  vq_prep<<<2, 256, 0, stream>>>(cb, sc, losses);
  vq_main<<<NPIX / 128, 256, 0, stream>>>(x, cb, sc, out, idx_out, losses);
}

// Round 6
// 226.068 us; speedup vs baseline: 1.1094x; 1.1094x over previous
//
#include <hip/hip_runtime.h>

#define NK 512
#define ND 64
#define NHW 4096
#define NPIX 131072            // 32*64*64
#define OUT_ELEMS 8388608      // 32*64*64*64
#define RS 80                  // packed codebook row stride (floats): 64 data + sc + pad

typedef float f4 __attribute__((ext_vector_type(4)));

// Packed codebook: row k = {cb[k][0..63], sc[k], 15 pad}; 513 rows (row 512 is
// a phantom target for the last prefetch, never consumed). Module global so we
// don't depend on ws_size; rewritten by vq_prep every launch (stream-ordered
// before vq_main).
__device__ __attribute__((aligned(64))) float cbp[513 * RS];

// ---------------------------------------------------------------------------
// Prep: pack codebook + sc (numpy-pairwise-8 fp32 sum of fl(c_d^2)); zero the
// two loss slots (harness re-poisons d_out/d_ws to 0xAA every replay).
// ---------------------------------------------------------------------------
__global__ __launch_bounds__(256) void vq_prep(const float* __restrict__ cb,
                                               float* __restrict__ losses) {
#pragma clang fp contract(off)
  {
    const int k = blockIdx.x * 256 + threadIdx.x;   // grid 2*256 = 512
    const float* c = cb + (size_t)k * ND;
    float* dst = cbp + (size_t)k * RS;

    f4 v[16];
#pragma unroll
    for (int dq = 0; dq < 16; ++dq) {
      v[dq] = *(const f4*)(c + dq * 4);
      *(f4*)(dst + dq * 4) = v[dq];
    }
    // Pairwise-8 sum of rounded squares (bitwise = all passing rounds).
    float rr[8];
    rr[0] = v[0][0] * v[0][0]; rr[1] = v[0][1] * v[0][1];
    rr[2] = v[0][2] * v[0][2]; rr[3] = v[0][3] * v[0][3];
    rr[4] = v[1][0] * v[1][0]; rr[5] = v[1][1] * v[1][1];
    rr[6] = v[1][2] * v[1][2]; rr[7] = v[1][3] * v[1][3];
#pragma unroll
    for (int i = 2; i < 16; i += 2) {
      rr[0] += v[i][0] * v[i][0];     rr[1] += v[i][1] * v[i][1];
      rr[2] += v[i][2] * v[i][2];     rr[3] += v[i][3] * v[i][3];
      rr[4] += v[i + 1][0] * v[i + 1][0]; rr[5] += v[i + 1][1] * v[i + 1][1];
      rr[6] += v[i + 1][2] * v[i + 1][2]; rr[7] += v[i + 1][3] * v[i + 1][3];
    }
    dst[64] = ((rr[0] + rr[1]) + (rr[2] + rr[3])) + ((rr[4] + rr[5]) + (rr[6] + rr[7]));
    if (k < 2) losses[k] = 0.f;
  }
}

// ---- asm building blocks -------------------------------------------------
// x load: strided global dword into pinned VGPR, then bump addr by 16 KB.
#define XLD(VD)                                          \
  "global_load_dword " VD ", v[48:49], off\n\t"          \
  "v_add_co_u32 v48, vcc, 0x4000, v48\n\t"               \
  "v_addc_co_u32 v49, vcc, 0, v49, vcc\n\t"
#define SQ0(R, V) "v_mul_f32 " R ", " V ", " V "\n\t"
#define SQA(R, V) "v_fmac_f32 " R ", " V ", " V "\n\t"
#define FM(S, V)  "v_fmac_f32 v54, " S ", " V "\n\t"

// ---------------------------------------------------------------------------
// Main: lane = pixel. R4/R5 post-mortem: VGPR_Count 44-48 (< the 64 x needs)
// and VALU time 2.1x the FMA floor -> compiler kept x on the AGPR side /
// shuttled SGPR tuples via v_mov, one extra VALU op per FMA; "+v" pins and
// tie-removal changed nothing. R6 takes allocation away from the compiler:
// ONE asm block owns the hot loop with hard-pinned registers:
//   v48:49 addr | v52 code ctr | v53 d2 | v54 acc | v55 Sx | v56-63 rr |
//   v64-127 x | s28 sc | s29 cnt | s30:31 row addr | s36-99 A/B tuples.
// Per code: issue B(dims 32-63)+sc; 32 FMAs on A; lgkmcnt(0); bump; issue
// A'(next code dims 0-31); 32 FMAs on B; combine+argmin; lgkmcnt(0).
// Each wait is covered by a 32-FMA dependent chain (~128 cyc).
// K split: waves 0,1 -> codes 0..255; waves 2,3 -> 256..511; same 128
// pixels; 1024 blocks = 4 blocks/CU = 4 waves/SIMD at the 128-VGPR budget.
// Loss now comes from m (min d2) instead of a fresh (x-q)^2 pass: per-pixel
// rounding diff ~1e-5 -> mean shift <1e-8, inside the tolerance already
// absorbing our reduction-order differences.
// Numerics of out/idx bit-identical: v_mul + 63 v_fmac ascending d (= fma
// chain from 0); d2 = fma(a,-2,Sx) (+sc) = fl(fl(Sx-fl(2a))+Sc) since 2a is
// exact; Sx/sc pairwise-8; ascending codes, strict '<'; cross-half tie
// keeps the low half's lower index = np.argmin.
// ---------------------------------------------------------------------------
__global__ __launch_bounds__(256, 4) void vq_main(const float* __restrict__ x,
                                                  const float* __restrict__ cb,
                                                  float* __restrict__ out,
                                                  float* __restrict__ idx_out,
                                                  float* __restrict__ losses) {
#pragma clang fp contract(off)
  {
    __shared__ float him[128];
    __shared__ int   hii[128];
    __shared__ float red[2];

    const int tid = threadIdx.x;
    const int wv = tid >> 6;                 // 0..3
    const int lane = tid & 63;
    const int pxl = ((wv & 1) << 6) | lane;  // local pixel 0..127
    const int px = blockIdx.x * 128 + pxl;
    const int b = px >> 12;
    const int hw = px & 4095;

    const unsigned long long xa =
        (unsigned long long)(const void*)(x + (size_t)b * (ND * NHW) + hw);
    const unsigned int xlo = (unsigned int)xa;
    const unsigned int xhi = (unsigned int)(xa >> 32);

    const int k0 = (wv >> 1) << 8;           // 0 or 256 (wave-uniform)
    const unsigned long long ra =
        (unsigned long long)(const void*)cbp + (unsigned long long)k0 * (RS * 4);
    const unsigned int rlo = __builtin_amdgcn_readfirstlane((unsigned int)ra);
    const unsigned int rhi = __builtin_amdgcn_readfirstlane((unsigned int)(ra >> 32));
    const unsigned long long rowa = ((unsigned long long)rhi << 32) | rlo;
    const int k0s = __builtin_amdgcn_readfirstlane(k0);

    float m = 3.0e38f;
    int best = 0;

    asm volatile(
      // ---- prologue: addresses, counters, first A issue, x load, Sx.
      "s_mov_b64 s[30:31], %[rw]\n\t"
      "v_mov_b32 v48, %[xlo]\n\t"
      "v_mov_b32 v49, %[xhi]\n\t"
      "v_mov_b32 v52, %[k0]\n\t"
      "s_load_dwordx16 s[36:51], s[30:31], 0x0\n\t"
      "s_load_dwordx16 s[52:67], s[30:31], 0x40\n\t"
      XLD("v64")  XLD("v65")  XLD("v66")  XLD("v67")
      XLD("v68")  XLD("v69")  XLD("v70")  XLD("v71")
      XLD("v72")  XLD("v73")  XLD("v74")  XLD("v75")
      XLD("v76")  XLD("v77")  XLD("v78")  XLD("v79")
      XLD("v80")  XLD("v81")  XLD("v82")  XLD("v83")
      XLD("v84")  XLD("v85")  XLD("v86")  XLD("v87")
      XLD("v88")  XLD("v89")  XLD("v90")  XLD("v91")
      XLD("v92")  XLD("v93")  XLD("v94")  XLD("v95")
      XLD("v96")  XLD("v97")  XLD("v98")  XLD("v99")
      XLD("v100") XLD("v101") XLD("v102") XLD("v103")
      XLD("v104") XLD("v105") XLD("v106") XLD("v107")
      XLD("v108") XLD("v109") XLD("v110") XLD("v111")
      XLD("v112") XLD("v113") XLD("v114") XLD("v115")
      XLD("v116") XLD("v117") XLD("v118") XLD("v119")
      XLD("v120") XLD("v121") XLD("v122") XLD("v123")
      XLD("v124") XLD("v125") XLD("v126") XLD("v127")
      "s_waitcnt vmcnt(0)\n\t"
      // Sx: rr[j] = x[j]^2; rr[j] += x[8i+j]^2 (i=1..7); pairwise tree.
      SQ0("v56","v64") SQ0("v57","v65") SQ0("v58","v66") SQ0("v59","v67")
      SQ0("v60","v68") SQ0("v61","v69") SQ0("v62","v70") SQ0("v63","v71")
      SQA("v56","v72")  SQA("v57","v73")  SQA("v58","v74")  SQA("v59","v75")
      SQA("v60","v76")  SQA("v61","v77")  SQA("v62","v78")  SQA("v63","v79")
      SQA("v56","v80")  SQA("v57","v81")  SQA("v58","v82")  SQA("v59","v83")
      SQA("v60","v84")  SQA("v61","v85")  SQA("v62","v86")  SQA("v63","v87")
      SQA("v56","v88")  SQA("v57","v89")  SQA("v58","v90")  SQA("v59","v91")
      SQA("v60","v92")  SQA("v61","v93")  SQA("v62","v94")  SQA("v63","v95")
      SQA("v56","v96")  SQA("v57","v97")  SQA("v58","v98")  SQA("v59","v99")
      SQA("v60","v100") SQA("v61","v101") SQA("v62","v102") SQA("v63","v103")
      SQA("v56","v104") SQA("v57","v105") SQA("v58","v106") SQA("v59","v107")
      SQA("v60","v108") SQA("v61","v109") SQA("v62","v110") SQA("v63","v111")
      SQA("v56","v112") SQA("v57","v113") SQA("v58","v114") SQA("v59","v115")
      SQA("v60","v116") SQA("v61","v117") SQA("v62","v118") SQA("v63","v119")
      SQA("v56","v120") SQA("v57","v121") SQA("v58","v122") SQA("v59","v123")
      SQA("v60","v124") SQA("v61","v125") SQA("v62","v126") SQA("v63","v127")
      "v_add_f32 v56, v56, v57\n\t"
      "v_add_f32 v58, v58, v59\n\t"
      "v_add_f32 v60, v60, v61\n\t"
      "v_add_f32 v62, v62, v63\n\t"
      "v_add_f32 v56, v56, v58\n\t"
      "v_add_f32 v60, v60, v62\n\t"
      "v_add_f32 v55, v56, v60\n\t"
      "s_mov_b32 s29, 0x100\n\t"
      "s_waitcnt lgkmcnt(0)\n\t"
      // ---- K loop: 256 codes.
      "Lvq%=:\n\t"
      "s_load_dwordx16 s[68:83], s[30:31], 0x80\n\t"
      "s_load_dwordx16 s[84:99], s[30:31], 0xc0\n\t"
      "s_load_dword s28, s[30:31], 0x100\n\t"
      "v_mul_f32 v54, s36, v64\n\t"
      FM("s37","v65") FM("s38","v66") FM("s39","v67")
      FM("s40","v68") FM("s41","v69") FM("s42","v70") FM("s43","v71")
      FM("s44","v72") FM("s45","v73") FM("s46","v74") FM("s47","v75")
      FM("s48","v76") FM("s49","v77") FM("s50","v78") FM("s51","v79")
      FM("s52","v80") FM("s53","v81") FM("s54","v82") FM("s55","v83")
      FM("s56","v84") FM("s57","v85") FM("s58","v86") FM("s59","v87")
      FM("s60","v88") FM("s61","v89") FM("s62","v90") FM("s63","v91")
      FM("s64","v92") FM("s65","v93") FM("s66","v94") FM("s67","v95")
      "s_waitcnt lgkmcnt(0)\n\t"
      "s_add_u32 s30, s30, 0x140\n\t"
      "s_addc_u32 s31, s31, 0\n\t"
      "s_load_dwordx16 s[36:51], s[30:31], 0x0\n\t"
      "s_load_dwordx16 s[52:67], s[30:31], 0x40\n\t"
      FM("s68","v96")  FM("s69","v97")  FM("s70","v98")  FM("s71","v99")
      FM("s72","v100") FM("s73","v101") FM("s74","v102") FM("s75","v103")
      FM("s76","v104") FM("s77","v105") FM("s78","v106") FM("s79","v107")
      FM("s80","v108") FM("s81","v109") FM("s82","v110") FM("s83","v111")
      FM("s84","v112") FM("s85","v113") FM("s86","v114") FM("s87","v115")
      FM("s88","v116") FM("s89","v117") FM("s90","v118") FM("s91","v119")
      FM("s92","v120") FM("s93","v121") FM("s94","v122") FM("s95","v123")
      FM("s96","v124") FM("s97","v125") FM("s98","v126") FM("s99","v127")
      "v_fma_f32 v53, v54, -2.0, v55\n\t"
      "v_add_f32 v53, s28, v53\n\t"
      "v_cmp_lt_f32 vcc, v53, %[mm]\n\t"
      "v_cndmask_b32 %[mm], %[mm], v53, vcc\n\t"
      "v_cndmask_b32 %[bb], %[bb], v52, vcc\n\t"
      "v_add_u32 v52, 1, v52\n\t"
      "s_sub_u32 s29, s29, 1\n\t"
      "s_waitcnt lgkmcnt(0)\n\t"
      "s_cmp_lg_u32 s29, 0\n\t"
      "s_cbranch_scc1 Lvq%=\n\t"
      : [mm] "+v"(m), [bb] "+v"(best)
      : [xlo] "v"(xlo), [xhi] "v"(xhi), [rw] "s"(rowa), [k0] "s"(k0s)
      : "vcc", "scc",
        "s28","s29","s30","s31",
        "s36","s37","s38","s39","s40","s41","s42","s43",
        "s44","s45","s46","s47","s48","s49","s50","s51",
        "s52","s53","s54","s55","s56","s57","s58","s59",
        "s60","s61","s62","s63","s64","s65","s66","s67",
        "s68","s69","s70","s71","s72","s73","s74","s75",
        "s76","s77","s78","s79","s80","s81","s82","s83",
        "s84","s85","s86","s87","s88","s89","s90","s91",
        "s92","s93","s94","s95","s96","s97","s98","s99",
        "v48","v49","v50","v51","v52","v53","v54","v55",
        "v56","v57","v58","v59","v60","v61","v62","v63",
        "v64","v65","v66","v67","v68","v69","v70","v71",
        "v72","v73","v74","v75","v76","v77","v78","v79",
        "v80","v81","v82","v83","v84","v85","v86","v87",
        "v88","v89","v90","v91","v92","v93","v94","v95",
        "v96","v97","v98","v99","v100","v101","v102","v103",
        "v104","v105","v106","v107","v108","v109","v110","v111",
        "v112","v113","v114","v115","v116","v117","v118","v119",
        "v120","v121","v122","v123","v124","v125","v126","v127");

    // ---- Cross-half argmin: high half publishes; low half combines with
    // strict '<' (tie keeps low half's lower index = np.argmin).
    if (wv >= 2) { him[pxl] = m; hii[pxl] = best; }
    __syncthreads();

    float lossp = 0.f;
    if (wv < 2) {
      const float mh = him[pxl];
      const int ih = hii[pxl];
      if (mh < m) { m = mh; best = ih; }
      idx_out[px] = (float)best;
      const float* qrow = cb + (size_t)best * ND;
      float* op = out + (size_t)b * (ND * NHW) + hw;
#pragma unroll
      for (int dq = 0; dq < 16; ++dq) {
        const f4 qv = *(const f4*)(qrow + dq * 4);
        op[(size_t)(dq * 4 + 0) * NHW] = qv[0];
        op[(size_t)(dq * 4 + 1) * NHW] = qv[1];
        op[(size_t)(dq * 4 + 2) * NHW] = qv[2];
        op[(size_t)(dq * 4 + 3) * NHW] = qv[3];
      }
      lossp = m;   // min d2 == ||x - q||^2 (within ~1e-5 rounding)
    }
#pragma unroll
    for (int off = 32; off; off >>= 1) lossp += __shfl_down(lossp, off);
    if (lane == 0 && wv < 2) red[wv] = lossp;
    __syncthreads();
    if (tid == 0) {
      float t = (red[0] + red[1]) * (1.f / 8388608.f);
      atomicAdd(losses + 0, t);   // dictionary_loss
      atomicAdd(losses + 1, t);   // commitment_loss (identical forward value)
    }
  }
}

extern "C" void kernel_launch(void* const* d_in, const int* in_sizes, int n_in,
                              void* d_out, int out_size, void* d_ws, size_t ws_size,
                              hipStream_t stream) {
  const float* x  = (const float*)d_in[0];   // [32,64,64,64] fp32
  const float* cb = (const float*)d_in[1];   // [512,64] fp32
  float* out     = (float*)d_out;            // quantized [B,D,H,W]
  float* idx_out = out + OUT_ELEMS;          // indices (as fp32) [B,H,W]
  float* losses  = idx_out + NPIX;           // 2 scalars
  (void)d_ws; (void)ws_size;                 // packed codebook lives in a module global

  vq_prep<<<2, 256, 0, stream>>>(cb, losses);
  vq_main<<<NPIX / 128, 256, 0, stream>>>(x, cb, out, idx_out, losses);
}